// Round 3
// baseline (310.541 us; speedup 1.0000x reference)
//
#include <hip/hip_runtime.h>
#include <hip/hip_bf16.h>
#include <math.h>

#define BS 32
#define NQ 900
#define NC 91
#define NT 30
#define NJ (BS*NT)            // 960
#define C3_SZ ((size_t)BS*NQ*NJ)
#define NROWS (BS*NQ)         // 28800

#define LT 960                // block size (15 waves)
#define LWAVES (LT/64)        // 15
#define NCOSTBLK 512
#define MAXROWS 64            // max rows per cost block (28800/512 = 56.25)

__device__ __forceinline__ float fast_rcp(float x) { return __builtin_amdgcn_rcpf(x); }

struct SharedLSA {
    float  cst[NT * NQ];      // 108000 B  cst[r*NQ+q]
    float  mx[NQ];
    float  rs[NQ];
    double u[NT + 1];
    int    p[NQ + 1];
    int    way[NQ + 1];
    double red_v[LWAVES];
    int    red_i[LWAVES];
    int    rows[NT];
    int    tl[NT];
    float4 tbox[NT];
};
struct SharedCost {
    float mx[MAXROWS];
    float rs[MAXROWS];
};

// cost element for (query row `row` params, target regs); returns C value
__device__ __forceinline__ float cost_elem(
    float pcx, float pcy, float pw, float ph,
    float px0, float py0, float px1, float py1, float area_a,
    float pr,                       // class prob at this target's label
    float tcx, float tcy, float tw, float th,
    float tx0, float ty0, float tx1, float ty1, float area_b)
{
    float cost_bbox = fabsf(pcx - tcx) + fabsf(pcy - tcy) + fabsf(pw - tw) + fabsf(ph - th);
    float ix0 = fmaxf(px0, tx0), iy0 = fmaxf(py0, ty0);
    float ix1 = fminf(px1, tx1), iy1 = fminf(py1, ty1);
    float inter = fmaxf(ix1 - ix0, 0.f) * fmaxf(iy1 - iy0, 0.f);
    float uni = area_a + area_b - inter;
    float iou = inter * fast_rcp(uni);
    float ex0 = fminf(px0, tx0), ey0 = fminf(py0, ty0);
    float ex1 = fmaxf(px1, tx1), ey1 = fmaxf(py1, ty1);
    float encl = fmaxf(ex1 - ex0, 0.f) * fmaxf(ey1 - ey0, 0.f);
    float giou = iou - (encl - uni) * fast_rcp(encl);
    // C = 5*bbox + (1-prob) + 2*(1-giou) = 5*bbox - prob - 2*giou + 3
    return 5.0f * cost_bbox - pr - 2.0f * giou + 3.0f;
}

__global__ __launch_bounds__(LT) void fused_kernel(
    const float* __restrict__ logits,   // (NROWS, NC)
    const float* __restrict__ pboxes,   // (NROWS, 4)
    const int*   __restrict__ tlabels,  // (NJ)
    const float* __restrict__ tboxes,   // (NJ, 4)
    float* __restrict__ out,            // (NROWS, NJ)
    float* __restrict__ outp,           // (BS, NT)
    float* __restrict__ outt)           // (BS, NT)
{
    __shared__ union { SharedLSA l; SharedCost c; } sm;
    const int t = threadIdx.x;

    if (blockIdx.x < BS) {
        // ================= LSA block for batch b =================
        const int b = blockIdx.x;
        const float* lg = logits + (size_t)b * NQ * NC;
        const float* pbx = pboxes + (size_t)b * NQ * 4;

        // phase A: per-query softmax max & 1/sumexp
        for (int q = t; q < NQ; q += LT) {
            const float* r = lg + (size_t)q * NC;
            float m = -1e30f;
            for (int c = 0; c < NC; ++c) m = fmaxf(m, r[c]);
            float s = 0.f;
            for (int c = 0; c < NC; ++c) s += __expf(r[c] - m);
            sm.l.mx[q] = m;
            sm.l.rs[q] = fast_rcp(s);
        }
        if (t < NT) {
            sm.l.tl[t] = tlabels[b * NT + t];
            sm.l.tbox[t] = ((const float4*)tboxes)[b * NT + t];
        }
        for (int j = t; j <= NQ; j += LT) { sm.l.p[j] = 0; sm.l.way[j] = 0; }
        if (t <= NT) sm.l.u[t] = 0.0;
        __syncthreads();

        // phase B: fill cst[r*NQ+q]
        for (int e = t; e < NT * NQ; e += LT) {
            int q = e / NT;
            int r = e - q * NT;
            float4 pb = ((const float4*)pbx)[q];
            float pcx = pb.x, pcy = pb.y, pw = pb.z, ph = pb.w;
            float px0 = pcx - 0.5f*pw, py0 = pcy - 0.5f*ph;
            float px1 = pcx + 0.5f*pw, py1 = pcy + 0.5f*ph;
            float area_a = pw * ph;
            int   lbl = sm.l.tl[r];
            float pr = __expf(lg[(size_t)q * NC + lbl] - sm.l.mx[q]) * sm.l.rs[q];
            float4 tb = sm.l.tbox[r];
            float tcx = tb.x, tcy = tb.y, tw = tb.z, th = tb.w;
            float tx0 = tcx - 0.5f*tw, ty0 = tcy - 0.5f*th;
            float tx1 = tcx + 0.5f*tw, ty1 = tcy + 0.5f*th;
            float area_b = tw * th;
            sm.l.cst[r * NQ + q] = cost_elem(pcx, pcy, pw, ph, px0, py0, px1, py1, area_a,
                                             pr, tcx, tcy, tw, th, tx0, ty0, tx1, ty1, area_b);
        }
        double v_t = 0.0;
        __syncthreads();

        // ---- Jonker-Volgenant, f64 state, exact numpy op order ----
        for (int i = 1; i <= NT; ++i) {
            double minv_t = 1e18;
            bool used_t = (t == 0);
            int p_t = (t == 0) ? i : ((t <= NQ) ? sm.l.p[t] : 0);
            int i0 = i, j0 = 0, j1f = 0;
            for (;;) {
                double u_i0 = sm.l.u[i0];
                double cand; int ci;
                if (t >= 1 && t <= NQ && !used_t) {
                    double cur = ((double)sm.l.cst[(i0 - 1) * NQ + (t - 1)] - u_i0) - v_t;
                    if (cur < minv_t) { minv_t = cur; sm.l.way[t] = j0; }
                    cand = minv_t; ci = t;
                } else { cand = 1e18; ci = 1 << 20; }
                // in-wave argmin (first-index tie-break)
                for (int off = 32; off; off >>= 1) {
                    double ov = __shfl_xor(cand, off);
                    int    oi = __shfl_xor(ci, off);
                    if (ov < cand || (ov == cand && oi < ci)) { cand = ov; ci = oi; }
                }
                int wv = t >> 6;
                if ((t & 63) == 0) { sm.l.red_v[wv] = cand; sm.l.red_i[wv] = ci; }
                __syncthreads();                                   // (A)
                int ll = t & 63;
                double rv; int ri;
                if (ll < LWAVES) { rv = sm.l.red_v[ll]; ri = sm.l.red_i[ll]; }
                else             { rv = 1e18;           ri = 1 << 20; }
                for (int off = 8; off; off >>= 1) {
                    double ov = __shfl_xor(rv, off);
                    int    oi = __shfl_xor(ri, off);
                    if (ov < rv || (ov == rv && oi < ri)) { rv = ov; ri = oi; }
                }
                double delta = __shfl(rv, 0);
                int    j1    = __shfl(ri, 0);
                if (used_t) { v_t -= delta; sm.l.u[p_t] += delta; }
                else if (t >= 1 && t <= NQ) minv_t -= delta;
                if (t == j1) used_t = true;
                int pj1 = sm.l.p[j1];
                __syncthreads();                                   // (B)
                if (pj1 == 0) { j1f = j1; break; }
                i0 = pj1; j0 = j1;
            }
            if (t == 0) {
                int j0w = j1f;
                while (j0w) {
                    int jp = sm.l.way[j0w];
                    sm.l.p[j0w] = (jp == 0) ? i : sm.l.p[jp];
                    j0w = jp;
                }
            }
            __syncthreads();                                       // (C)
        }
        if (t >= 1 && t <= NQ && sm.l.p[t] > 0) sm.l.rows[sm.l.p[t] - 1] = t - 1;
        __syncthreads();
        if (t == 0) {
            int pr[NT], tg[NT];
            for (int r = 0; r < NT; ++r) { pr[r] = sm.l.rows[r]; tg[r] = r; }
            for (int a = 1; a < NT; ++a) {
                int kp = pr[a], kt = tg[a]; int bnd = a - 1;
                while (bnd >= 0 && pr[bnd] > kp) { pr[bnd+1] = pr[bnd]; tg[bnd+1] = tg[bnd]; --bnd; }
                pr[bnd+1] = kp; tg[bnd+1] = kt;
            }
            for (int k = 0; k < NT; ++k) {
                outp[b*NT + k] = (float)pr[k];
                outt[b*NT + k] = (float)tg[k];
            }
        }
    } else {
        // ================= C3 writer block =================
        const int cb = blockIdx.x - BS;                 // 0..511
        const int r0 = (int)(((long long)cb * NROWS) / NCOSTBLK);
        const int r1 = (int)(((long long)(cb + 1) * NROWS) / NCOSTBLK);
        const int nrows = r1 - r0;

        // phase 1: softmax params for this block's rows
        for (int rr = t; rr < nrows; rr += LT) {
            const float* r = logits + (size_t)(r0 + rr) * NC;
            float m = -1e30f;
            for (int c = 0; c < NC; ++c) m = fmaxf(m, r[c]);
            float s = 0.f;
            for (int c = 0; c < NC; ++c) s += __expf(r[c] - m);
            sm.c.mx[rr] = m;
            sm.c.rs[rr] = fast_rcp(s);
        }
        // per-thread persistent target regs (t = target column)
        int   lbl = tlabels[t];
        float4 tb = ((const float4*)tboxes)[t];
        float tcx = tb.x, tcy = tb.y, tw = tb.z, th = tb.w;
        float tx0 = tcx - 0.5f*tw, ty0 = tcy - 0.5f*th;
        float tx1 = tcx + 0.5f*tw, ty1 = tcy + 0.5f*th;
        float area_b = tw * th;
        __syncthreads();

        // phase 2: one row per iteration, thread t writes column t
        for (int rr = 0; rr < nrows; ++rr) {
            const int row = r0 + rr;
            float lgv = logits[(size_t)row * NC + lbl];          // L1/L2 gather
            float pr = __expf(lgv - sm.c.mx[rr]) * sm.c.rs[rr];
            float4 pb = ((const float4*)pboxes)[row];            // uniform
            float pcx = pb.x, pcy = pb.y, pw = pb.z, ph = pb.w;
            float px0 = pcx - 0.5f*pw, py0 = pcy - 0.5f*ph;
            float px1 = pcx + 0.5f*pw, py1 = pcy + 0.5f*ph;
            float area_a = pw * ph;
            out[(size_t)row * NJ + t] =
                cost_elem(pcx, pcy, pw, ph, px0, py0, px1, py1, area_a,
                          pr, tcx, tcy, tw, th, tx0, ty0, tx1, ty1, area_b);
        }
    }
}

extern "C" void kernel_launch(void* const* d_in, const int* in_sizes, int n_in,
                              void* d_out, int out_size, void* d_ws, size_t ws_size,
                              hipStream_t stream) {
    const float* logits  = (const float*)d_in[0];
    const float* pboxes  = (const float*)d_in[1];
    const int*   tlabels = (const int*)d_in[2];
    const float* tboxes  = (const float*)d_in[3];
    float* out = (float*)d_out;

    fused_kernel<<<BS + NCOSTBLK, LT, 0, stream>>>(
        logits, pboxes, tlabels, tboxes,
        out, out + C3_SZ, out + C3_SZ + (size_t)BS * NT);
}

// Round 4
// 220.675 us; speedup vs baseline: 1.4072x; 1.4072x over previous
//
#include <hip/hip_runtime.h>
#include <hip/hip_bf16.h>
#include <math.h>

#define BS 32
#define NQ 900
#define NC 91
#define NT 30
#define NJ (BS*NT)            // 960
#define C3_SZ ((size_t)BS*NQ*NJ)
#define NROWS (BS*NQ)         // 28800

#define LT 960                // block size (15 waves)
#define LWAVES (LT/64)        // 15
#define NCOSTBLK 224          // 32 LSA + 224 writers = 256 blocks, all resident
#define MAXROWS 132           // ceil(28800/224)=129

__device__ __forceinline__ float fast_rcp(float x) { return __builtin_amdgcn_rcpf(x); }

struct SharedLSA {
    float  cst[NT * NQ];      // 108000 B  cst[r*NQ+q]
    float  mx[NQ];
    float  rs[NQ];
    double u[NT + 1];
    int    p[NQ + 1];
    int    way[NQ + 1];
    double red_v[LWAVES];
    int    red_i[LWAVES];
    int    rows[NT];
    int    tl[NT];
    float4 tbox[NT];
    float  rminv[NT];         // greedy: per-row min value
    int    rminc[NT];         // greedy: per-row argmin column (1-based)
    int    aflag[NT + 1];     // greedy: row assigned?
};
struct SharedCost {
    float mx[MAXROWS];
    float rs[MAXROWS];
};

__device__ __forceinline__ float cost_elem(
    float pcx, float pcy, float pw, float ph,
    float px0, float py0, float px1, float py1, float area_a,
    float pr,
    float tcx, float tcy, float tw, float th,
    float tx0, float ty0, float tx1, float ty1, float area_b)
{
    float cost_bbox = fabsf(pcx - tcx) + fabsf(pcy - tcy) + fabsf(pw - tw) + fabsf(ph - th);
    float ix0 = fmaxf(px0, tx0), iy0 = fmaxf(py0, ty0);
    float ix1 = fminf(px1, tx1), iy1 = fminf(py1, ty1);
    float inter = fmaxf(ix1 - ix0, 0.f) * fmaxf(iy1 - iy0, 0.f);
    float uni = area_a + area_b - inter;
    float iou = inter * fast_rcp(uni);
    float ex0 = fminf(px0, tx0), ey0 = fminf(py0, ty0);
    float ex1 = fmaxf(px1, tx1), ey1 = fmaxf(py1, ty1);
    float encl = fmaxf(ex1 - ex0, 0.f) * fmaxf(ey1 - ey0, 0.f);
    float giou = iou - (encl - uni) * fast_rcp(encl);
    return 5.0f * cost_bbox - pr - 2.0f * giou + 3.0f;   // 5*bbox + (1-p) + 2*(1-giou)
}

// coalesced softmax params for one row: lanes 0..63 cover 91 logits
__device__ __forceinline__ void softmax_row(const float* __restrict__ lrow, int lane,
                                            float* out_mx, float* out_rs)
{
    float a = (lane < NC)      ? lrow[lane]      : -1e30f;
    float c = (lane + 64 < NC) ? lrow[lane + 64] : -1e30f;
    float m = fmaxf(a, c);
    for (int off = 32; off; off >>= 1) m = fmaxf(m, __shfl_xor(m, off));
    float ea = (lane < NC)      ? __expf(a - m) : 0.f;
    float ec = (lane + 64 < NC) ? __expf(c - m) : 0.f;
    float s = ea + ec;
    for (int off = 32; off; off >>= 1) s += __shfl_xor(s, off);
    if (lane == 0) { *out_mx = m; *out_rs = fast_rcp(s); }
}

__global__ __launch_bounds__(LT) void fused_kernel(
    const float* __restrict__ logits,   // (NROWS, NC)
    const float* __restrict__ pboxes,   // (NROWS, 4)
    const int*   __restrict__ tlabels,  // (NJ)
    const float* __restrict__ tboxes,   // (NJ, 4)
    float* __restrict__ out,            // (NROWS, NJ)
    float* __restrict__ outp,           // (BS, NT)
    float* __restrict__ outt)           // (BS, NT)
{
    __shared__ union { SharedLSA l; SharedCost c; } sm;
    const int t = threadIdx.x;
    const int wv = t >> 6;
    const int lane = t & 63;

    if (blockIdx.x < BS) {
        // ================= LSA block for batch b =================
        const int b = blockIdx.x;
        const float* lg  = logits + (size_t)b * NQ * NC;
        const float* pbx = pboxes + (size_t)b * NQ * 4;

        // phase A: per-query softmax params, wave-per-row coalesced
        for (int q = wv; q < NQ; q += LWAVES)
            softmax_row(lg + (size_t)q * NC, lane, &sm.l.mx[q], &sm.l.rs[q]);
        if (t < NT) {
            sm.l.tl[t] = tlabels[b * NT + t];
            sm.l.tbox[t] = ((const float4*)tboxes)[b * NT + t];
        }
        for (int j = t; j <= NQ; j += LT) { sm.l.p[j] = 0; sm.l.way[j] = 0; }
        __syncthreads();

        // phase B: fill cst[r*NQ+q]
        for (int e = t; e < NT * NQ; e += LT) {
            int q = e / NT;
            int r = e - q * NT;
            float4 pb = ((const float4*)pbx)[q];
            float pcx = pb.x, pcy = pb.y, pw = pb.z, ph = pb.w;
            float px0 = pcx - 0.5f*pw, py0 = pcy - 0.5f*ph;
            float px1 = pcx + 0.5f*pw, py1 = pcy + 0.5f*ph;
            float area_a = pw * ph;
            int   lbl = sm.l.tl[r];
            float pr = __expf(lg[(size_t)q * NC + lbl] - sm.l.mx[q]) * sm.l.rs[q];
            float4 tb = sm.l.tbox[r];
            float tcx = tb.x, tcy = tb.y, tw = tb.z, th = tb.w;
            float tx0 = tcx - 0.5f*tw, ty0 = tcy - 0.5f*th;
            float tx1 = tcx + 0.5f*tw, ty1 = tcy + 0.5f*th;
            float area_b = tw * th;
            sm.l.cst[r * NQ + q] = cost_elem(pcx, pcy, pw, ph, px0, py0, px1, py1, area_a,
                                             pr, tcx, tcy, tw, th, tx0, ty0, tx1, ty1, area_b);
        }
        __syncthreads();

        // greedy init: per-row min + argmin (wave-per-row, coalesced LDS reads)
        for (int r = wv; r < NT; r += LWAVES) {
            float bv = 1e30f; int bi = 1 << 20;
            for (int j = lane; j < NQ; j += 64) {
                float v = sm.l.cst[r * NQ + j];
                if (v < bv) { bv = v; bi = j; }           // ascending j: first-min per lane
            }
            for (int off = 32; off; off >>= 1) {
                float ov = __shfl_xor(bv, off);
                int   oi = __shfl_xor(bi, off);
                if (ov < bv || (ov == bv && oi < bi)) { bv = ov; bi = oi; }
            }
            if (lane == 0) { sm.l.rminv[r] = bv; sm.l.rminc[r] = bi + 1; }
        }
        __syncthreads();
        // dual-feasible greedy claim (u[i]=rowmin, v=0, CS holds); conflicts -> Dijkstra
        if (t == 0) {
            for (int r = 1; r <= NT; ++r) {
                sm.l.u[r] = (double)sm.l.rminv[r - 1];
                int c = sm.l.rminc[r - 1];
                if (sm.l.p[c] == 0) { sm.l.p[c] = r; sm.l.aflag[r] = 1; }
                else                 sm.l.aflag[r] = 0;
            }
        }
        double v_t = 0.0;
        __syncthreads();

        // ---- JV Dijkstra only for unassigned rows (verified 15-wave core) ----
        for (int i = 1; i <= NT; ++i) {
            if (sm.l.aflag[i]) continue;                   // uniform branch
            double minv_t = 1e18;
            bool used_t = (t == 0);
            int p_t = (t == 0) ? i : ((t <= NQ) ? sm.l.p[t] : 0);
            int i0 = i, j0 = 0, j1f = 0;
            for (;;) {
                double u_i0 = sm.l.u[i0];
                double cand; int ci;
                if (t >= 1 && t <= NQ && !used_t) {
                    double cur = ((double)sm.l.cst[(i0 - 1) * NQ + (t - 1)] - u_i0) - v_t;
                    if (cur < minv_t) { minv_t = cur; sm.l.way[t] = j0; }
                    cand = minv_t; ci = t;
                } else { cand = 1e18; ci = 1 << 20; }
                for (int off = 32; off; off >>= 1) {
                    double ov = __shfl_xor(cand, off);
                    int    oi = __shfl_xor(ci, off);
                    if (ov < cand || (ov == cand && oi < ci)) { cand = ov; ci = oi; }
                }
                if (lane == 0) { sm.l.red_v[wv] = cand; sm.l.red_i[wv] = ci; }
                __syncthreads();                                   // (A)
                double rv; int ri;
                if (lane < LWAVES) { rv = sm.l.red_v[lane]; ri = sm.l.red_i[lane]; }
                else               { rv = 1e18;             ri = 1 << 20; }
                for (int off = 8; off; off >>= 1) {
                    double ov = __shfl_xor(rv, off);
                    int    oi = __shfl_xor(ri, off);
                    if (ov < rv || (ov == rv && oi < ri)) { rv = ov; ri = oi; }
                }
                double delta = __shfl(rv, 0);
                int    j1    = __shfl(ri, 0);
                if (used_t) { v_t -= delta; sm.l.u[p_t] += delta; }
                else if (t >= 1 && t <= NQ) minv_t -= delta;
                if (t == j1) { used_t = true; p_t = sm.l.p[j1]; }
                int pj1 = sm.l.p[j1];
                __syncthreads();                                   // (B)
                if (pj1 == 0) { j1f = j1; break; }
                i0 = pj1; j0 = j1;
            }
            if (t == 0) {
                int j0w = j1f;
                while (j0w) {
                    int jp = sm.l.way[j0w];
                    sm.l.p[j0w] = (jp == 0) ? i : sm.l.p[jp];
                    j0w = jp;
                }
            }
            __syncthreads();                                       // (C)
        }
        if (t >= 1 && t <= NQ && sm.l.p[t] > 0) sm.l.rows[sm.l.p[t] - 1] = t - 1;
        __syncthreads();
        if (t == 0) {
            int pr[NT], tg[NT];
            for (int r = 0; r < NT; ++r) { pr[r] = sm.l.rows[r]; tg[r] = r; }
            for (int a = 1; a < NT; ++a) {
                int kp = pr[a], kt = tg[a]; int bnd = a - 1;
                while (bnd >= 0 && pr[bnd] > kp) { pr[bnd+1] = pr[bnd]; tg[bnd+1] = tg[bnd]; --bnd; }
                pr[bnd+1] = kp; tg[bnd+1] = kt;
            }
            for (int k = 0; k < NT; ++k) {
                outp[b*NT + k] = (float)pr[k];
                outt[b*NT + k] = (float)tg[k];
            }
        }
    } else {
        // ================= C3 writer block =================
        const int cb = blockIdx.x - BS;                 // 0..223
        const int r0 = (int)(((long long)cb * NROWS) / NCOSTBLK);
        const int r1 = (int)(((long long)(cb + 1) * NROWS) / NCOSTBLK);
        const int nrows = r1 - r0;

        // phase 1: softmax params, wave-per-row coalesced
        for (int rr = wv; rr < nrows; rr += LWAVES)
            softmax_row(logits + (size_t)(r0 + rr) * NC, lane, &sm.c.mx[rr], &sm.c.rs[rr]);

        int   lbl = tlabels[t];
        float4 tb = ((const float4*)tboxes)[t];
        float tcx = tb.x, tcy = tb.y, tw = tb.z, th = tb.w;
        float tx0 = tcx - 0.5f*tw, ty0 = tcy - 0.5f*th;
        float tx1 = tcx + 0.5f*tw, ty1 = tcy + 0.5f*th;
        float area_b = tw * th;
        __syncthreads();

        // phase 2: one row per iteration, thread t writes column t
        for (int rr = 0; rr < nrows; ++rr) {
            const int row = r0 + rr;
            float lgv = logits[(size_t)row * NC + lbl];
            float pr = __expf(lgv - sm.c.mx[rr]) * sm.c.rs[rr];
            float4 pb = ((const float4*)pboxes)[row];
            float pcx = pb.x, pcy = pb.y, pw = pb.z, ph = pb.w;
            float px0 = pcx - 0.5f*pw, py0 = pcy - 0.5f*ph;
            float px1 = pcx + 0.5f*pw, py1 = pcy + 0.5f*ph;
            float area_a = pw * ph;
            out[(size_t)row * NJ + t] =
                cost_elem(pcx, pcy, pw, ph, px0, py0, px1, py1, area_a,
                          pr, tcx, tcy, tw, th, tx0, ty0, tx1, ty1, area_b);
        }
    }
}

extern "C" void kernel_launch(void* const* d_in, const int* in_sizes, int n_in,
                              void* d_out, int out_size, void* d_ws, size_t ws_size,
                              hipStream_t stream) {
    const float* logits  = (const float*)d_in[0];
    const float* pboxes  = (const float*)d_in[1];
    const int*   tlabels = (const int*)d_in[2];
    const float* tboxes  = (const float*)d_in[3];
    float* out = (float*)d_out;

    fused_kernel<<<BS + NCOSTBLK, LT, 0, stream>>>(
        logits, pboxes, tlabels, tboxes,
        out, out + C3_SZ, out + C3_SZ + (size_t)BS * NT);
}